// Round 5
// baseline (187.806 us; speedup 1.0000x reference)
//
#include <hip/hip_runtime.h>
#include <hip/hip_bf16.h>

__device__ __forceinline__ float sigm(float x) { return 1.f / (1.f + expf(-x)); }
__device__ __forceinline__ float lrelu(float x) { return x > 0.f ? x : 0.2f * x; }
__device__ __forceinline__ float eluf(float x) { return x > 0.f ? x : expf(x) - 1.f; }

#define NEGF (-9e15f)
#define MAXD 64   // max supported out-degree; P(deg>64) ~ 1e-40 for Binom(4096,1/512)

__device__ __forceinline__ float wave_sum(float v) {
    #pragma unroll
    for (int off = 32; off >= 1; off >>= 1) v += __shfl_xor(v, off);
    return v;
}
__device__ __forceinline__ float wave_max(float v) {
    #pragma unroll
    for (int off = 32; off >= 1; off >>= 1) v = fmaxf(v, __shfl_xor(v, off));
    return v;
}

// ---------------- K1: SingleNodeAttention: h = elu(coef * (feat @ W_sn)) ----------------
// grid 512, block 64
__global__ void k_sn(const float* __restrict__ feat, const float* __restrict__ Wsn,
                     const float* __restrict__ asn, float* __restrict__ h) {
    int n = blockIdx.x, t = threadIdx.x;
    __shared__ float fr[64];
    fr[t] = feat[n * 64 + t];
    __syncthreads();
    float acc = 0.f;
    #pragma unroll 8
    for (int i = 0; i < 64; i++) acc += fr[i] * Wsn[i * 64 + t];
    float p = wave_sum(acc * asn[t]);
    float coef = sigm(lrelu(p));
    h[n * 64 + t] = eluf(coef * acc);
}

// ---------------- gate1[n] = sigm(h[n]·g1W + b), wave per node ----------------
// grid 128, block 256
__global__ void k_gate1(const float* __restrict__ h, const float* __restrict__ gW,
                        const float* __restrict__ gb, float* __restrict__ gate) {
    int node = blockIdx.x * 4 + (threadIdx.x >> 6), l = threadIdx.x & 63;
    float v = wave_sum(h[node * 64 + l] * gW[l]);
    if (l == 0) gate[node] = sigm(v + gb[0]);
}

// ---------------- wsum1 partial: grid 8 (n-chunks), block 512 ----------------
__global__ void k_wsum1p(const float* __restrict__ h, const float* __restrict__ gate,
                         float* __restrict__ part1) {
    int nb = blockIdx.x, t = threadIdx.x, w = t >> 6, l = t & 63;
    __shared__ float mx[8], sm[8], al[512], pt[8][64];
    float g = gate[t];
    float m = wave_max(g);
    if (l == 0) mx[w] = m;
    __syncthreads();
    m = mx[0];
    #pragma unroll
    for (int i = 1; i < 8; i++) m = fmaxf(m, mx[i]);
    float p = expf(g - m);
    float Z = wave_sum(p);
    if (l == 0) sm[w] = Z;
    __syncthreads();
    Z = 0.f;
    #pragma unroll
    for (int i = 0; i < 8; i++) Z += sm[i];
    al[t] = p / Z;
    __syncthreads();
    int r0 = nb * 64 + w * 8;
    float acc = 0.f;
    #pragma unroll
    for (int r = 0; r < 8; r++) acc += al[r0 + r] * h[(r0 + r) * 64 + l];
    pt[w][l] = acc;
    __syncthreads();
    if (t < 64) {
        float o = 0.f;
        #pragma unroll
        for (int q = 0; q < 8; q++) o += pt[q][t];
        part1[nb * 64 + t] = o;
    }
}

// ---------------- K3: GAT1 Wh = h @ Wg, es = Wh.a_src, ed = Wh.a_dst ----------------
// grid (512, 16), block 128
__global__ void k_gat1_wh(const float* __restrict__ h, const float* __restrict__ Wg,
                          const float* __restrict__ asrc, const float* __restrict__ adst,
                          float* __restrict__ Wh, float* __restrict__ es, float* __restrict__ ed) {
    int n = blockIdx.x, hd = blockIdx.y, t = threadIdx.x;
    __shared__ float hr[64];
    __shared__ float r0[2], r1[2];
    if (t < 64) hr[t] = h[n * 64 + t];
    __syncthreads();
    float acc = 0.f;
    const float* W = Wg + (size_t)hd * 64 * 128;
    #pragma unroll 8
    for (int i = 0; i < 64; i++) acc += hr[i] * W[i * 128 + t];
    Wh[(size_t)(hd * 512 + n) * 128 + t] = acc;
    float ps = wave_sum(acc * asrc[hd * 128 + t]);
    float pd = wave_sum(acc * adst[hd * 128 + t]);
    if ((t & 63) == 0) { r0[t >> 6] = ps; r1[t >> 6] = pd; }
    __syncthreads();
    if (t == 0) { es[hd * 512 + n] = r0[0] + r0[1]; ed[hd * 512 + n] = r1[0] + r1[1]; }
}

// ---------------- K4: ve1[h,i] = sum_o Weg[h,i,o]*a_edge[h,o] ----------------
// grid 16, block 64
__global__ void k_ve1(const float* __restrict__ Weg, const float* __restrict__ ae,
                      float* __restrict__ ve1) {
    int hd = blockIdx.x, i = threadIdx.x;
    float acc = 0.f;
    for (int o = 0; o < 128; o++) acc += Weg[((size_t)hd * 64 + i) * 128 + o] * ae[hd * 128 + o];
    ve1[hd * 64 + i] = acc;
}

// ---------------- K4b: ve2[c] = sum_o Weo[c,o]*ao_edge[o] ----------------
// grid 16, block 128
__global__ void k_ve2(const float* __restrict__ Weo, const float* __restrict__ aoe,
                      float* __restrict__ ve2) {
    int c = blockIdx.x * 128 + threadIdx.x;
    float acc = 0.f;
    for (int o = 0; o < 128; o++) acc += Weo[(size_t)c * 128 + o] * aoe[o];
    ve2[c] = acc;
}

// ---------------- K5: scatter last-wins winner edge per (src/2, dst/2) slot ----------------
// grid 16, block 256
__global__ void k_scatter(const int* __restrict__ ei, int* __restrict__ winner) {
    int e = blockIdx.x * 256 + threadIdx.x;
    if (e < 4096) {
        int s = ei[e] >> 1;
        int d = ei[4096 + e] >> 1;
        atomicMax(&winner[s * 256 + d], e);   // last edge index wins (np .set semantics)
    }
}

// ---------------- FUSED K6+K7: sparse attention + hout per source row ----------------
// grid 512 (s), block 512
__global__ void k_attn_hout(const float* __restrict__ es, const float* __restrict__ ed,
                            const float* __restrict__ adj, const float* __restrict__ n2n,
                            const float* __restrict__ ve1, const float* __restrict__ Wh,
                            float* __restrict__ hout) {
    int s = blockIdx.x, t = threadIdx.x, w = t >> 6, l = t & 63;
    __shared__ float vlT[64][16];      // ve1 transposed: vlT[i][hd]
    __shared__ float nrow[MAXD][65];   // staged n2n rows (padded)
    __shared__ float eh[16][MAXD];
    __shared__ float ah[16][MAXD];
    __shared__ float esr[16];
    __shared__ int dlist[MAXD];
    __shared__ int wbase[8];
    __shared__ int nnz_s;

    for (int idx = t; idx < 1024; idx += 512) vlT[idx & 63][idx >> 6] = ve1[idx];
    if (t < 16) esr[t] = es[t * 512 + s];
    __syncthreads();

    // 1. deterministic compaction of nonzero adj entries (ascending d)
    float a = adj[s * 512 + t];
    unsigned long long mask = __ballot(a > 0.f);
    int lcnt = __popcll(mask & ((1ULL << l) - 1ULL));
    if (l == 0) wbase[w] = __popcll(mask);
    __syncthreads();
    if (t == 0) {
        int run = 0;
        #pragma unroll
        for (int i = 0; i < 8; i++) { int c = wbase[i]; wbase[i] = run; run += c; }
        nnz_s = run;
    }
    __syncthreads();
    if (a > 0.f) {
        int slot = wbase[w] + lcnt;
        if (slot < MAXD) dlist[slot] = t;
    }
    __syncthreads();
    int nnz = min(nnz_s, MAXD);

    if (nnz > 0) {
        // 2. stage n2n rows (coalesced, 8 rows per pass)
        for (int base = 0; base < nnz; base += 8) {
            int j = base + (t >> 6);
            if (j < nnz) nrow[j][l] = n2n[((size_t)s * 512 + dlist[j]) * 64 + l];
        }
        __syncthreads();
        // 3. logits e[hd][j]
        for (int jb = 0; jb < nnz; jb += 32) {
            int j = jb + (t >> 4), hd = t & 15;
            if (j < nnz) {
                float ee = 0.f;
                #pragma unroll 8
                for (int i = 0; i < 64; i++) ee += nrow[j][i] * vlT[i][hd];
                eh[hd][j] = lrelu(esr[hd] + ed[hd * 512 + dlist[j]] + ee);
            }
        }
        __syncthreads();
        // 4. per-head softmax over nnz entries (masked entries are exact zeros)
        if (t < 16) {
            float m = -1e30f;
            for (int j = 0; j < nnz; j++) m = fmaxf(m, eh[t][j]);
            float Z = 0.f;
            for (int j = 0; j < nnz; j++) { float p = expf(eh[t][j] - m); ah[t][j] = p; Z += p; }
            float inv = 1.f / Z;
            for (int j = 0; j < nnz; j++) ah[t][j] *= inv;
        }
        __syncthreads();
        // 5. hout[s][hd*128+c] = elu( sum_j a[hd][j] * Wh[hd][dlist[j]][c] )
        int c = t & 127, hd0 = t >> 7;
        #pragma unroll
        for (int k = 0; k < 4; k++) {
            int hd = hd0 + 4 * k;
            float acc = 0.f;
            for (int j = 0; j < nnz; j++)
                acc += ah[hd][j] * Wh[((size_t)hd * 512 + dlist[j]) * 128 + c];
            hout[(size_t)s * 2048 + hd * 128 + c] = eluf(acc);
        }
    } else {
        // empty row: softmax over all-NEG = uniform 1/512
        int c = t & 127, hd0 = t >> 7;
        #pragma unroll
        for (int k = 0; k < 4; k++) {
            int hd = hd0 + 4 * k;
            float acc = 0.f;
            for (int d = 0; d < 512; d++) acc += Wh[((size_t)hd * 512 + d) * 128 + c];
            hout[(size_t)s * 2048 + hd * 128 + c] = eluf(acc * (1.f / 512.f));
        }
    }
}

// ---------------- K8: per-edge d2[e] = sum_c elu(edge_attr[e] @ Weg)[c] * ve2[c] ----------------
// grid 512 (8 edges/block), block 256
__global__ void k_edot(const float* __restrict__ eattr, const float* __restrict__ Weg,
                       const float* __restrict__ ve2, float* __restrict__ d2) {
    int e0 = blockIdx.x * 8, t = threadIdx.x;
    int w = t >> 6, l = t & 63;
    __shared__ float ea[8][64];
    __shared__ float sd[8][4];
    for (int idx = t; idx < 8 * 64; idx += 256)
        ea[idx >> 6][idx & 63] = eattr[(size_t)(e0 + (idx >> 6)) * 64 + (idx & 63)];
    __syncthreads();
    int hd = t >> 4, o0 = (t & 15) * 8;
    float acc[8][8];
    #pragma unroll
    for (int r = 0; r < 8; r++)
        #pragma unroll
        for (int j = 0; j < 8; j++) acc[r][j] = 0.f;
    const float* W = Weg + (size_t)hd * 64 * 128 + o0;
    for (int i = 0; i < 64; i++) {
        float wv[8];
        #pragma unroll
        for (int j = 0; j < 8; j++) wv[j] = W[i * 128 + j];
        #pragma unroll
        for (int r = 0; r < 8; r++) {
            float a = ea[r][i];
            #pragma unroll
            for (int j = 0; j < 8; j++) acc[r][j] += a * wv[j];
        }
    }
    float v2[8];
    #pragma unroll
    for (int j = 0; j < 8; j++) v2[j] = ve2[hd * 128 + o0 + j];
    #pragma unroll
    for (int r = 0; r < 8; r++) {
        float p = 0.f;
        #pragma unroll
        for (int j = 0; j < 8; j++) p += eluf(acc[r][j]) * v2[j];
        p = wave_sum(p);
        if (l == 0) sd[r][w] = p;
    }
    __syncthreads();
    if (t < 8) d2[e0 + t] = sd[t][0] + sd[t][1] + sd[t][2] + sd[t][3];
}

// ---------------- K9: edge_pool1 ----------------
// grid 256, block 256
__global__ void k_pool1(const float* __restrict__ x, const float* __restrict__ Wp,
                        const float* __restrict__ bp, float* __restrict__ xo) {
    int k = blockIdx.x, t = threadIdx.x, w = t >> 6, l = t & 63;
    __shared__ float sd[4];
    float p = 0.f;
    for (int f = t; f < 2048; f += 256)
        p += x[(size_t)(2 * k) * 2048 + f] * Wp[f] + x[(size_t)(2 * k + 1) * 2048 + f] * Wp[2048 + f];
    p = wave_sum(p);
    if (l == 0) sd[w] = p;
    __syncthreads();
    float sc = sigm(sd[0] + sd[1] + sd[2] + sd[3] + bp[0]);
    for (int f = t; f < 2048; f += 256)
        xo[(size_t)k * 2048 + f] = (x[(size_t)(2 * k) * 2048 + f] + x[(size_t)(2 * k + 1) * 2048 + f]) * sc;
}

// ---------------- gate2[n] = sigm(x1p[n]·g2W + b), block per node ----------------
// grid 256, block 256
__global__ void k_gate2(const float* __restrict__ x, const float* __restrict__ gW,
                        const float* __restrict__ gb, float* __restrict__ gate) {
    int n = blockIdx.x, t = threadIdx.x, w = t >> 6, l = t & 63;
    __shared__ float sd[4];
    float p = 0.f;
    #pragma unroll
    for (int k = 0; k < 8; k++) {
        int c = t + 256 * k;
        p += x[(size_t)n * 2048 + c] * gW[c];
    }
    p = wave_sum(p);
    if (l == 0) sd[w] = p;
    __syncthreads();
    if (t == 0) gate[n] = sigm(sd[0] + sd[1] + sd[2] + sd[3] + gb[0]);
}

// ---------------- wsum2 partial: grid (8 col-blk, 8 n-blk), block 256 ----------------
__global__ void k_wsum2p(const float* __restrict__ x, const float* __restrict__ gate,
                         float* __restrict__ part2) {
    int t = threadIdx.x, w = t >> 6, l = t & 63;
    __shared__ float mx[4], sm[4], al[256];
    float g = gate[t];
    float m = wave_max(g);
    if (l == 0) mx[w] = m;
    __syncthreads();
    m = fmaxf(fmaxf(mx[0], mx[1]), fmaxf(mx[2], mx[3]));
    float p = expf(g - m);
    float Z = wave_sum(p);
    if (l == 0) sm[w] = Z;
    __syncthreads();
    Z = sm[0] + sm[1] + sm[2] + sm[3];
    al[t] = p / Z;
    __syncthreads();
    int c = blockIdx.x * 256 + t;
    int n0 = blockIdx.y * 32;
    float acc = 0.f;
    #pragma unroll 8
    for (int n = n0; n < n0 + 32; n++) acc += al[n] * x[(size_t)n * 2048 + c];
    part2[blockIdx.y * 2048 + c] = acc;
}

// ---------------- reducer for wsum1 + wsum2 ----------------
// grid 9, block 256
__global__ void k_wsumr(const float* __restrict__ part1, const float* __restrict__ part2,
                        float* __restrict__ out) {
    int b = blockIdx.x, t = threadIdx.x;
    if (b == 0) {
        if (t < 64) {
            float o = 0.f;
            #pragma unroll
            for (int nb = 0; nb < 8; nb++) o += part1[nb * 64 + t];
            out[t] = o;
        }
    } else {
        int c = (b - 1) * 256 + t;
        float o = 0.f;
        #pragma unroll
        for (int nb = 0; nb < 8; nb++) o += part2[nb * 2048 + c];
        out[64 + c] = o;
    }
}

// ---------------- K11: Wh2 = x1p @ Wo, es2/ed2 — K-split, 16 waves/block ----------------
// grid 256, block 1024
__global__ void k_wh2(const float* __restrict__ x, const float* __restrict__ Wo,
                      const float* __restrict__ aos, const float* __restrict__ aod,
                      float* __restrict__ Wh2, float* __restrict__ es2, float* __restrict__ ed2) {
    int n = blockIdx.x, t = threadIdx.x;
    int ks = t >> 7, c = t & 127;
    __shared__ float xr[2048];
    __shared__ float part[8][128];
    __shared__ float r0[2], r1[2];
    for (int i = t; i < 2048; i += 1024) xr[i] = x[(size_t)n * 2048 + i];
    __syncthreads();
    float acc = 0.f;
    const float* W = Wo + (size_t)(ks * 256) * 128 + c;
    const float* xk = xr + ks * 256;
    #pragma unroll 8
    for (int i = 0; i < 256; i++) acc += xk[i] * W[(size_t)i * 128];
    part[ks][c] = acc;
    __syncthreads();
    float a = 0.f;
    if (t < 128) {
        #pragma unroll
        for (int k = 0; k < 8; k++) a += part[k][t];
        Wh2[n * 128 + t] = a;
    }
    float ps = (t < 128) ? a * aos[t] : 0.f;
    float pd = (t < 128) ? a * aod[t] : 0.f;
    ps = wave_sum(ps);
    pd = wave_sum(pd);
    if (t < 128 && (t & 63) == 0) { r0[t >> 6] = ps; r1[t >> 6] = pd; }
    __syncthreads();
    if (t == 0) { es2[n] = r0[0] + r0[1]; ed2[n] = r1[0] + r1[1]; }
}

// ---------------- K12: GAT2 attention + hout2 ----------------
// grid 256, block 256
__global__ void k_attn2(const int* __restrict__ winner, const float* __restrict__ d2,
                        const float* __restrict__ es2, const float* __restrict__ ed2,
                        const float* __restrict__ Wh2, float* __restrict__ hout2) {
    int s = blockIdx.x, t = threadIdx.x, w = t >> 6, l = t & 63;
    __shared__ float mx[4], sm[4], at[256], part[2][128];
    int win = winner[s * 256 + t];
    float e;
    if (win >= 0) e = lrelu(es2[s] + ed2[t] + d2[win]);
    else e = NEGF;
    float m = wave_max(e);
    if (l == 0) mx[w] = m;
    __syncthreads();
    m = fmaxf(fmaxf(mx[0], mx[1]), fmaxf(mx[2], mx[3]));
    float p = expf(e - m);
    float Z = wave_sum(p);
    if (l == 0) sm[w] = Z;
    __syncthreads();
    Z = sm[0] + sm[1] + sm[2] + sm[3];
    at[t] = p / Z;
    __syncthreads();
    int c = t & 127, hf = t >> 7;
    float acc = 0.f;
    for (int d = hf * 128; d < hf * 128 + 128; d++)
        acc += at[d] * Wh2[d * 128 + c];
    part[hf][c] = acc;
    __syncthreads();
    if (t < 128) hout2[s * 128 + t] = part[0][t] + part[1][t];   // concat=False: no elu
}

// ---------------- K13: edge_pool2 ----------------
// grid 128, block 128
__global__ void k_pool2(const float* __restrict__ x, const float* __restrict__ Wp,
                        const float* __restrict__ bp, float* __restrict__ xo) {
    int k = blockIdx.x, t = threadIdx.x;
    __shared__ float r[2];
    float a0 = x[(size_t)(2 * k) * 128 + t];
    float a1 = x[(size_t)(2 * k + 1) * 128 + t];
    float p = wave_sum(a0 * Wp[t] + a1 * Wp[128 + t]);
    if ((t & 63) == 0) r[t >> 6] = p;
    __syncthreads();
    float sc = sigm(r[0] + r[1] + bp[0]);
    xo[k * 128 + t] = (a0 + a1) * sc;
}

// ---------------- gate3[n] = sigm(x2p[n]·g3W + b), wave per node ----------------
// grid 32, block 256
__global__ void k_gate3(const float* __restrict__ x, const float* __restrict__ gW,
                        const float* __restrict__ gb, float* __restrict__ gate) {
    int node = blockIdx.x * 4 + (threadIdx.x >> 6), l = threadIdx.x & 63;
    float v = x[node * 128 + l] * gW[l] + x[node * 128 + 64 + l] * gW[64 + l];
    v = wave_sum(v);
    if (l == 0) gate[node] = sigm(v + gb[0]);
}

// ---------------- wsum3: out[2112+c], in-block n-split ----------------
// grid 1, block 512
__global__ void k_wsum3(const float* __restrict__ x, const float* __restrict__ gate,
                        float* __restrict__ out) {
    int t = threadIdx.x;
    __shared__ float mx[2], sm[2], al[128], part[4][128];
    if (t < 128) {
        int w = t >> 6, l = t & 63;
        float g = gate[t];
        float m = wave_max(g);
        if (l == 0) mx[w] = m;
    }
    __syncthreads();
    if (t < 128) {
        int w = t >> 6, l = t & 63;
        float g = gate[t];
        float m = fmaxf(mx[0], mx[1]);
        float p = expf(g - m);
        float Z = wave_sum(p);
        if (l == 0) sm[w] = Z;
        al[t] = p;
    }
    __syncthreads();
    float invZ = 1.f / (sm[0] + sm[1]);
    int q = t >> 7, c = t & 127;
    float acc = 0.f;
    for (int n = q * 32; n < q * 32 + 32; n++) acc += al[n] * x[n * 128 + c];
    part[q][c] = acc * invZ;
    __syncthreads();
    if (t < 128) out[2112 + t] = part[0][t] + part[1][t] + part[2][t] + part[3][t];
}

extern "C" void kernel_launch(void* const* d_in, const int* in_sizes, int n_in,
                              void* d_out, int out_size, void* d_ws, size_t ws_size,
                              hipStream_t stream) {
    const float* feat  = (const float*)d_in[0];
    const int*   eidx  = (const int*)d_in[1];
    const float* eattr = (const float*)d_in[2];
    const float* adj   = (const float*)d_in[3];
    const float* n2n   = (const float*)d_in[4];
    const float* Wsn   = (const float*)d_in[5];
    const float* asn   = (const float*)d_in[6];
    const float* Wg    = (const float*)d_in[7];
    const float* Weg   = (const float*)d_in[8];
    const float* asrc  = (const float*)d_in[9];
    const float* adst  = (const float*)d_in[10];
    const float* aedge = (const float*)d_in[11];
    const float* Wp1   = (const float*)d_in[12];
    const float* bp1   = (const float*)d_in[13];
    const float* Wo    = (const float*)d_in[14];
    const float* Weo   = (const float*)d_in[15];
    const float* aos   = (const float*)d_in[16];
    const float* aod   = (const float*)d_in[17];
    const float* aoe   = (const float*)d_in[18];
    const float* Wp2   = (const float*)d_in[19];
    const float* bp2   = (const float*)d_in[20];
    const float* g1W   = (const float*)d_in[21];
    const float* g1b   = (const float*)d_in[22];
    const float* g2W   = (const float*)d_in[23];
    const float* g2b   = (const float*)d_in[24];
    const float* g3W   = (const float*)d_in[25];
    const float* g3b   = (const float*)d_in[26];
    float* out = (float*)d_out;

    char* ws = (char*)d_ws;
    float* h      = (float*)(ws + 0x0000000);   // 128KB
    float* Wh1    = (float*)(ws + 0x0020000);   // 4MB
    float* es1    = (float*)(ws + 0x0420000);   // 32KB
    float* ed1    = (float*)(ws + 0x0428000);   // 32KB
    float* ve1    = (float*)(ws + 0x0430000);   // 4KB
    float* ve2    = (float*)(ws + 0x0431000);   // 8KB
    float* gate1  = (float*)(ws + 0x0433000);   // 2KB
    float* gate2  = (float*)(ws + 0x0434000);   // 1KB
    float* gate3  = (float*)(ws + 0x0435000);   // 0.5KB
    float* hout1  = (float*)(ws + 0x1440000);   // 4MB
    float* d2     = (float*)(ws + 0x1840000);   // 16KB
    float* x1p    = (float*)(ws + 0x1850000);   // 2MB
    int*   winner = (int*)  (ws + 0x1A50000);   // 256KB
    float* Wh2    = (float*)(ws + 0x1A90000);   // 128KB
    float* es2    = (float*)(ws + 0x1AB0000);   // 1KB
    float* ed2    = (float*)(ws + 0x1AB1000);   // 1KB
    float* hout2  = (float*)(ws + 0x1AB2000);   // 128KB
    float* x2p    = (float*)(ws + 0x1AD2000);   // 64KB
    float* part2  = (float*)(ws + 0x1AE2000);   // 64KB
    float* part1  = (float*)(ws + 0x1AF2000);   // 2KB

    hipMemsetAsync(winner, 0xFF, 65536 * sizeof(int), stream);   // winner = -1

    k_sn       <<<512, 64, 0, stream>>>(feat, Wsn, asn, h);
    k_ve1      <<<16, 64, 0, stream>>>(Weg, aedge, ve1);
    k_ve2      <<<16, 128, 0, stream>>>(Weo, aoe, ve2);
    k_scatter  <<<16, 256, 0, stream>>>(eidx, winner);
    k_gate1    <<<128, 256, 0, stream>>>(h, g1W, g1b, gate1);
    k_wsum1p   <<<8, 512, 0, stream>>>(h, gate1, part1);
    k_gat1_wh  <<<dim3(512, 16), 128, 0, stream>>>(h, Wg, asrc, adst, Wh1, es1, ed1);
    k_attn_hout<<<512, 512, 0, stream>>>(es1, ed1, adj, n2n, ve1, Wh1, hout1);
    k_edot     <<<512, 256, 0, stream>>>(eattr, Weg, ve2, d2);
    k_pool1    <<<256, 256, 0, stream>>>(hout1, Wp1, bp1, x1p);
    k_gate2    <<<256, 256, 0, stream>>>(x1p, g2W, g2b, gate2);
    k_wsum2p   <<<dim3(8, 8), 256, 0, stream>>>(x1p, gate2, part2);
    k_wsumr    <<<9, 256, 0, stream>>>(part1, part2, out);
    k_wh2      <<<256, 1024, 0, stream>>>(x1p, Wo, aos, aod, Wh2, es2, ed2);
    k_attn2    <<<256, 256, 0, stream>>>(winner, d2, es2, ed2, Wh2, hout2);
    k_pool2    <<<128, 128, 0, stream>>>(hout2, Wp2, bp2, x2p);
    k_gate3    <<<32, 256, 0, stream>>>(x2p, g3W, g3b, gate3);
    k_wsum3    <<<1, 512, 0, stream>>>(x2p, gate3, out);
}

// Round 6
// 150.117 us; speedup vs baseline: 1.2511x; 1.2511x over previous
//
#include <hip/hip_runtime.h>
#include <hip/hip_bf16.h>

__device__ __forceinline__ float sigm(float x) { return 1.f / (1.f + expf(-x)); }
__device__ __forceinline__ float lrelu(float x) { return x > 0.f ? x : 0.2f * x; }
__device__ __forceinline__ float eluf(float x) { return x > 0.f ? x : expf(x) - 1.f; }

#define NEGF (-9e15f)
#define MAXD 64   // max supported out-degree; P(deg>64) ~ 1e-40 for Binom(4096,1/512)

__device__ __forceinline__ float wave_sum(float v) {
    #pragma unroll
    for (int off = 32; off >= 1; off >>= 1) v += __shfl_xor(v, off);
    return v;
}
__device__ __forceinline__ float wave_max(float v) {
    #pragma unroll
    for (int off = 32; off >= 1; off >>= 1) v = fmaxf(v, __shfl_xor(v, off));
    return v;
}

// ---------------- K1: SingleNodeAttention: h = elu(coef * (feat @ W_sn)) ----------------
// grid 512, block 64
__global__ void k_sn(const float* __restrict__ feat, const float* __restrict__ Wsn,
                     const float* __restrict__ asn, float* __restrict__ h) {
    int n = blockIdx.x, t = threadIdx.x;
    __shared__ float fr[64];
    fr[t] = feat[n * 64 + t];
    __syncthreads();
    float acc = 0.f;
    #pragma unroll 8
    for (int i = 0; i < 64; i++) acc += fr[i] * Wsn[i * 64 + t];
    float p = wave_sum(acc * asn[t]);
    float coef = sigm(lrelu(p));
    h[n * 64 + t] = eluf(coef * acc);
}

// ---------------- gate1[n] = sigm(h[n]·g1W + b), wave per node ----------------
// grid 128, block 256
__global__ void k_gate1(const float* __restrict__ h, const float* __restrict__ gW,
                        const float* __restrict__ gb, float* __restrict__ gate) {
    int node = blockIdx.x * 4 + (threadIdx.x >> 6), l = threadIdx.x & 63;
    float v = wave_sum(h[node * 64 + l] * gW[l]);
    if (l == 0) gate[node] = sigm(v + gb[0]);
}

// ---------------- wsum1 partial: grid 8 (n-chunks), block 512 ----------------
__global__ void k_wsum1p(const float* __restrict__ h, const float* __restrict__ gate,
                         float* __restrict__ part1) {
    int nb = blockIdx.x, t = threadIdx.x, w = t >> 6, l = t & 63;
    __shared__ float mx[8], sm[8], al[512], pt[8][64];
    float g = gate[t];
    float m = wave_max(g);
    if (l == 0) mx[w] = m;
    __syncthreads();
    m = mx[0];
    #pragma unroll
    for (int i = 1; i < 8; i++) m = fmaxf(m, mx[i]);
    float p = expf(g - m);
    float Z = wave_sum(p);
    if (l == 0) sm[w] = Z;
    __syncthreads();
    Z = 0.f;
    #pragma unroll
    for (int i = 0; i < 8; i++) Z += sm[i];
    al[t] = p / Z;
    __syncthreads();
    int r0 = nb * 64 + w * 8;
    float acc = 0.f;
    #pragma unroll
    for (int r = 0; r < 8; r++) acc += al[r0 + r] * h[(r0 + r) * 64 + l];
    pt[w][l] = acc;
    __syncthreads();
    if (t < 64) {
        float o = 0.f;
        #pragma unroll
        for (int q = 0; q < 8; q++) o += pt[q][t];
        part1[nb * 64 + t] = o;
    }
}

// ---------------- K_vecs: vs1/vd1[h,i] = Wg[h,i,:]·a_{src,dst}[h], ve1 = Weg[h,i,:]·a_edge[h] ----------------
// grid 16, block 64
__global__ void k_vecs(const float* __restrict__ Wg, const float* __restrict__ Weg,
                       const float* __restrict__ asrc, const float* __restrict__ adst,
                       const float* __restrict__ aedge,
                       float* __restrict__ vs1, float* __restrict__ vd1, float* __restrict__ ve1) {
    int hd = blockIdx.x, i = threadIdx.x;
    float aS = 0.f, aD = 0.f, aE = 0.f;
    const float* Wr = Wg  + ((size_t)hd * 64 + i) * 128;
    const float* Er = Weg + ((size_t)hd * 64 + i) * 128;
    for (int o = 0; o < 128; o++) {
        float w = Wr[o];
        aS += w * asrc[hd * 128 + o];
        aD += w * adst[hd * 128 + o];
        aE += Er[o] * aedge[hd * 128 + o];
    }
    vs1[hd * 64 + i] = aS;
    vd1[hd * 64 + i] = aD;
    ve1[hd * 64 + i] = aE;
}

// ---------------- K4b: ve2[c] = sum_o Weo[c,o]*ao_edge[o] ----------------
// grid 16, block 128
__global__ void k_ve2(const float* __restrict__ Weo, const float* __restrict__ aoe,
                      float* __restrict__ ve2) {
    int c = blockIdx.x * 128 + threadIdx.x;
    float acc = 0.f;
    for (int o = 0; o < 128; o++) acc += Weo[(size_t)c * 128 + o] * aoe[o];
    ve2[c] = acc;
}

// ---------------- K5: scatter last-wins winner edge per (src/2, dst/2) slot ----------------
// grid 16, block 256
__global__ void k_scatter(const int* __restrict__ ei, int* __restrict__ winner) {
    int e = blockIdx.x * 256 + threadIdx.x;
    if (e < 4096) {
        int s = ei[e] >> 1;
        int d = ei[4096 + e] >> 1;
        atomicMax(&winner[s * 256 + d], e);   // last edge index wins (np .set semantics)
    }
}

// ---------------- K_attn_z: sparse GAT1 attention -> z[s][hd][0:64] = sum_j a*h[d_j] ----------------
// grid 512 (s), block 512
__global__ void k_attn_z(const float* __restrict__ adj, const float* __restrict__ n2n,
                         const float* __restrict__ h, const float* __restrict__ ve1,
                         const float* __restrict__ vs1, const float* __restrict__ vd1,
                         float* __restrict__ z) {
    int s = blockIdx.x, t = threadIdx.x, w = t >> 6, l = t & 63;
    __shared__ float vlT[64][17], vsT[64][17], vdT[64][17];   // transposed vecs [i][hd], padded
    __shared__ float hsr[64];
    __shared__ float hrow[MAXD][65], nrow[MAXD][65];
    __shared__ float eh[16][65], ah[16][65];
    __shared__ float es_s[16];
    __shared__ int dlist[MAXD];
    __shared__ int wbase[8];
    __shared__ int nnz_s;

    for (int idx = t; idx < 1024; idx += 512) {
        int i = idx & 63, hd = idx >> 6;
        vlT[i][hd] = ve1[hd * 64 + i];
        vsT[i][hd] = vs1[hd * 64 + i];
        vdT[i][hd] = vd1[hd * 64 + i];
    }
    if (t < 64) hsr[t] = h[s * 64 + t];
    float a = adj[s * 512 + t];
    unsigned long long mask = __ballot(a > 0.f);
    if (l == 0) wbase[w] = __popcll(mask);
    __syncthreads();                                          // b1
    if (t == 0) {
        int run = 0;
        #pragma unroll
        for (int i = 0; i < 8; i++) { int c = wbase[i]; wbase[i] = run; run += c; }
        nnz_s = run;
    }
    __syncthreads();                                          // b2
    if (a > 0.f) {
        int slot = wbase[w] + __popcll(mask & ((1ULL << l) - 1ULL));
        if (slot < MAXD) dlist[slot] = t;
    }
    __syncthreads();                                          // b3
    int nnz = min(nnz_s, MAXD);

    if (nnz == 0) {
        // softmax over all-NEG = uniform 1/512: z[hd][:] = colmean(h) for every head
        __shared__ float part[8][64];
        int i = t & 63, q = t >> 6;
        float acc = 0.f;
        for (int d = q * 64; d < q * 64 + 64; d++) acc += h[d * 64 + i];
        part[q][i] = acc;
        __syncthreads();
        if (t < 64) {
            float sum = 0.f;
            #pragma unroll
            for (int q2 = 0; q2 < 8; q2++) sum += part[q2][t];
            float v = sum * (1.f / 512.f);
            for (int hd = 0; hd < 16; hd++) z[(size_t)s * 1024 + hd * 64 + t] = v;
        }
        return;
    }

    // stage h rows (L2-hot, 128KB total) + n2n rows (sparse HBM), 8 rows per pass
    for (int base = 0; base < nnz; base += 8) {
        int j = base + (t >> 6);
        if (j < nnz) {
            int d = dlist[j];
            hrow[j][l] = h[d * 64 + l];
            nrow[j][l] = n2n[((size_t)s * 512 + d) * 64 + l];
        }
    }
    if (t < 16) {   // es[hd] = h[s]·vs1[hd]
        float acc = 0.f;
        for (int i = 0; i < 64; i++) acc += hsr[i] * vsT[i][t];
        es_s[t] = acc;
    }
    __syncthreads();                                          // b4
    // logits: e[hd][j] = lrelu(es + h[d_j]·vd1[hd] + n2n_row·ve1[hd])
    for (int jb = 0; jb < nnz; jb += 32) {
        int j = jb + (t >> 4), hd = t & 15;
        if (j < nnz) {
            float ee = 0.f, edv = 0.f;
            #pragma unroll 8
            for (int i = 0; i < 64; i++) {
                ee  += nrow[j][i] * vlT[i][hd];
                edv += hrow[j][i] * vdT[i][hd];
            }
            eh[hd][j] = lrelu(es_s[hd] + edv + ee);
        }
    }
    __syncthreads();                                          // b5
    if (t < 16) {   // per-head softmax over nnz entries (masked entries are exact zeros)
        float m = -1e30f;
        for (int j = 0; j < nnz; j++) m = fmaxf(m, eh[t][j]);
        float Z = 0.f;
        for (int j = 0; j < nnz; j++) { float p = expf(eh[t][j] - m); ah[t][j] = p; Z += p; }
        float inv = 1.f / Z;
        for (int j = 0; j < nnz; j++) ah[t][j] *= inv;
    }
    __syncthreads();                                          // b6
    // z[s][hd][i] = sum_j ah[hd][j] * hrow[j][i]
    int hd = t >> 5, i0 = t & 31;
    float a0 = 0.f, a1 = 0.f;
    for (int j = 0; j < nnz; j++) {
        float aj = ah[hd][j];
        a0 += aj * hrow[j][i0];
        a1 += aj * hrow[j][i0 + 32];
    }
    z[(size_t)s * 1024 + hd * 64 + i0]      = a0;
    z[(size_t)s * 1024 + hd * 64 + i0 + 32] = a1;
}

// ---------------- K_houtg: hout[s][hd*128+c] = elu( z[s][hd]·Wg[hd][:,c] ) ----------------
// grid (64 s-tiles, 16 hd), block 128
__global__ void k_houtg(const float* __restrict__ z, const float* __restrict__ Wg,
                        float* __restrict__ hout) {
    int sb = blockIdx.x, hd = blockIdx.y, c = threadIdx.x;
    __shared__ float zt[8][64];
    int s0 = sb * 8;
    for (int idx = c; idx < 512; idx += 128) {
        int r = idx >> 6, i = idx & 63;
        zt[r][i] = z[(size_t)(s0 + r) * 1024 + hd * 64 + i];
    }
    __syncthreads();
    float acc[8] = {0, 0, 0, 0, 0, 0, 0, 0};
    const float* W = Wg + (size_t)hd * 8192 + c;
    #pragma unroll 8
    for (int i = 0; i < 64; i++) {
        float wv = W[(size_t)i * 128];
        #pragma unroll
        for (int r = 0; r < 8; r++) acc[r] += zt[r][i] * wv;
    }
    #pragma unroll
    for (int r = 0; r < 8; r++)
        hout[(size_t)(s0 + r) * 2048 + hd * 128 + c] = eluf(acc[r]);
}

// ---------------- K8: per-edge d2[e] = sum_c elu(edge_attr[e] @ Weg)[c] * ve2[c] ----------------
// grid 512 (8 edges/block), block 256
__global__ void k_edot(const float* __restrict__ eattr, const float* __restrict__ Weg,
                       const float* __restrict__ ve2, float* __restrict__ d2) {
    int e0 = blockIdx.x * 8, t = threadIdx.x;
    int w = t >> 6, l = t & 63;
    __shared__ float ea[8][64];
    __shared__ float sd[8][4];
    for (int idx = t; idx < 8 * 64; idx += 256)
        ea[idx >> 6][idx & 63] = eattr[(size_t)(e0 + (idx >> 6)) * 64 + (idx & 63)];
    __syncthreads();
    int hd = t >> 4, o0 = (t & 15) * 8;
    float acc[8][8];
    #pragma unroll
    for (int r = 0; r < 8; r++)
        #pragma unroll
        for (int j = 0; j < 8; j++) acc[r][j] = 0.f;
    const float* W = Weg + (size_t)hd * 64 * 128 + o0;
    for (int i = 0; i < 64; i++) {
        float wv[8];
        #pragma unroll
        for (int j = 0; j < 8; j++) wv[j] = W[i * 128 + j];
        #pragma unroll
        for (int r = 0; r < 8; r++) {
            float a = ea[r][i];
            #pragma unroll
            for (int j = 0; j < 8; j++) acc[r][j] += a * wv[j];
        }
    }
    float v2[8];
    #pragma unroll
    for (int j = 0; j < 8; j++) v2[j] = ve2[hd * 128 + o0 + j];
    #pragma unroll
    for (int r = 0; r < 8; r++) {
        float p = 0.f;
        #pragma unroll
        for (int j = 0; j < 8; j++) p += eluf(acc[r][j]) * v2[j];
        p = wave_sum(p);
        if (l == 0) sd[r][w] = p;
    }
    __syncthreads();
    if (t < 8) d2[e0 + t] = sd[t][0] + sd[t][1] + sd[t][2] + sd[t][3];
}

// ---------------- K9: edge_pool1 ----------------
// grid 256, block 256
__global__ void k_pool1(const float* __restrict__ x, const float* __restrict__ Wp,
                        const float* __restrict__ bp, float* __restrict__ xo) {
    int k = blockIdx.x, t = threadIdx.x, w = t >> 6, l = t & 63;
    __shared__ float sd[4];
    float p = 0.f;
    for (int f = t; f < 2048; f += 256)
        p += x[(size_t)(2 * k) * 2048 + f] * Wp[f] + x[(size_t)(2 * k + 1) * 2048 + f] * Wp[2048 + f];
    p = wave_sum(p);
    if (l == 0) sd[w] = p;
    __syncthreads();
    float sc = sigm(sd[0] + sd[1] + sd[2] + sd[3] + bp[0]);
    for (int f = t; f < 2048; f += 256)
        xo[(size_t)k * 2048 + f] = (x[(size_t)(2 * k) * 2048 + f] + x[(size_t)(2 * k + 1) * 2048 + f]) * sc;
}

// ---------------- gate2[n] = sigm(x1p[n]·g2W + b), block per node ----------------
// grid 256, block 256
__global__ void k_gate2(const float* __restrict__ x, const float* __restrict__ gW,
                        const float* __restrict__ gb, float* __restrict__ gate) {
    int n = blockIdx.x, t = threadIdx.x, w = t >> 6, l = t & 63;
    __shared__ float sd[4];
    float p = 0.f;
    #pragma unroll
    for (int k = 0; k < 8; k++) {
        int c = t + 256 * k;
        p += x[(size_t)n * 2048 + c] * gW[c];
    }
    p = wave_sum(p);
    if (l == 0) sd[w] = p;
    __syncthreads();
    if (t == 0) gate[n] = sigm(sd[0] + sd[1] + sd[2] + sd[3] + gb[0]);
}

// ---------------- wsum2 partial: grid (8 col-blk, 8 n-blk), block 256 ----------------
__global__ void k_wsum2p(const float* __restrict__ x, const float* __restrict__ gate,
                         float* __restrict__ part2) {
    int t = threadIdx.x, w = t >> 6, l = t & 63;
    __shared__ float mx[4], sm[4], al[256];
    float g = gate[t];
    float m = wave_max(g);
    if (l == 0) mx[w] = m;
    __syncthreads();
    m = fmaxf(fmaxf(mx[0], mx[1]), fmaxf(mx[2], mx[3]));
    float p = expf(g - m);
    float Z = wave_sum(p);
    if (l == 0) sm[w] = Z;
    __syncthreads();
    Z = sm[0] + sm[1] + sm[2] + sm[3];
    al[t] = p / Z;
    __syncthreads();
    int c = blockIdx.x * 256 + t;
    int n0 = blockIdx.y * 32;
    float acc = 0.f;
    #pragma unroll 8
    for (int n = n0; n < n0 + 32; n++) acc += al[n] * x[(size_t)n * 2048 + c];
    part2[blockIdx.y * 2048 + c] = acc;
}

// ---------------- reducer for wsum1 + wsum2 ----------------
// grid 9, block 256
__global__ void k_wsumr(const float* __restrict__ part1, const float* __restrict__ part2,
                        float* __restrict__ out) {
    int b = blockIdx.x, t = threadIdx.x;
    if (b == 0) {
        if (t < 64) {
            float o = 0.f;
            #pragma unroll
            for (int nb = 0; nb < 8; nb++) o += part1[nb * 64 + t];
            out[t] = o;
        }
    } else {
        int c = (b - 1) * 256 + t;
        float o = 0.f;
        #pragma unroll
        for (int nb = 0; nb < 8; nb++) o += part2[nb * 2048 + c];
        out[64 + c] = o;
    }
}

// ---------------- K11: Wh2 = x1p @ Wo, es2/ed2 — K-split, 16 waves/block ----------------
// grid 256, block 1024
__global__ void k_wh2(const float* __restrict__ x, const float* __restrict__ Wo,
                      const float* __restrict__ aos, const float* __restrict__ aod,
                      float* __restrict__ Wh2, float* __restrict__ es2, float* __restrict__ ed2) {
    int n = blockIdx.x, t = threadIdx.x;
    int ks = t >> 7, c = t & 127;
    __shared__ float xr[2048];
    __shared__ float part[8][128];
    __shared__ float r0[2], r1[2];
    for (int i = t; i < 2048; i += 1024) xr[i] = x[(size_t)n * 2048 + i];
    __syncthreads();
    float acc = 0.f;
    const float* W = Wo + (size_t)(ks * 256) * 128 + c;
    const float* xk = xr + ks * 256;
    #pragma unroll 8
    for (int i = 0; i < 256; i++) acc += xk[i] * W[(size_t)i * 128];
    part[ks][c] = acc;
    __syncthreads();
    float a = 0.f;
    if (t < 128) {
        #pragma unroll
        for (int k = 0; k < 8; k++) a += part[k][t];
        Wh2[n * 128 + t] = a;
    }
    float ps = (t < 128) ? a * aos[t] : 0.f;
    float pd = (t < 128) ? a * aod[t] : 0.f;
    ps = wave_sum(ps);
    pd = wave_sum(pd);
    if (t < 128 && (t & 63) == 0) { r0[t >> 6] = ps; r1[t >> 6] = pd; }
    __syncthreads();
    if (t == 0) { es2[n] = r0[0] + r0[1]; ed2[n] = r1[0] + r1[1]; }
}

// ---------------- K12: GAT2 attention + hout2 ----------------
// grid 256, block 256
__global__ void k_attn2(const int* __restrict__ winner, const float* __restrict__ d2,
                        const float* __restrict__ es2, const float* __restrict__ ed2,
                        const float* __restrict__ Wh2, float* __restrict__ hout2) {
    int s = blockIdx.x, t = threadIdx.x, w = t >> 6, l = t & 63;
    __shared__ float mx[4], sm[4], at[256], part[2][128];
    int win = winner[s * 256 + t];
    float e;
    if (win >= 0) e = lrelu(es2[s] + ed2[t] + d2[win]);
    else e = NEGF;
    float m = wave_max(e);
    if (l == 0) mx[w] = m;
    __syncthreads();
    m = fmaxf(fmaxf(mx[0], mx[1]), fmaxf(mx[2], mx[3]));
    float p = expf(e - m);
    float Z = wave_sum(p);
    if (l == 0) sm[w] = Z;
    __syncthreads();
    Z = sm[0] + sm[1] + sm[2] + sm[3];
    at[t] = p / Z;
    __syncthreads();
    int c = t & 127, hf = t >> 7;
    float acc = 0.f;
    for (int d = hf * 128; d < hf * 128 + 128; d++)
        acc += at[d] * Wh2[d * 128 + c];
    part[hf][c] = acc;
    __syncthreads();
    if (t < 128) hout2[s * 128 + t] = part[0][t] + part[1][t];   // concat=False: no elu
}

// ---------------- K13: edge_pool2 ----------------
// grid 128, block 128
__global__ void k_pool2(const float* __restrict__ x, const float* __restrict__ Wp,
                        const float* __restrict__ bp, float* __restrict__ xo) {
    int k = blockIdx.x, t = threadIdx.x;
    __shared__ float r[2];
    float a0 = x[(size_t)(2 * k) * 128 + t];
    float a1 = x[(size_t)(2 * k + 1) * 128 + t];
    float p = wave_sum(a0 * Wp[t] + a1 * Wp[128 + t]);
    if ((t & 63) == 0) r[t >> 6] = p;
    __syncthreads();
    float sc = sigm(r[0] + r[1] + bp[0]);
    xo[k * 128 + t] = (a0 + a1) * sc;
}

// ---------------- gate3[n] = sigm(x2p[n]·g3W + b), wave per node ----------------
// grid 32, block 256
__global__ void k_gate3(const float* __restrict__ x, const float* __restrict__ gW,
                        const float* __restrict__ gb, float* __restrict__ gate) {
    int node = blockIdx.x * 4 + (threadIdx.x >> 6), l = threadIdx.x & 63;
    float v = x[node * 128 + l] * gW[l] + x[node * 128 + 64 + l] * gW[64 + l];
    v = wave_sum(v);
    if (l == 0) gate[node] = sigm(v + gb[0]);
}

// ---------------- wsum3: out[2112+c], in-block n-split ----------------
// grid 1, block 512
__global__ void k_wsum3(const float* __restrict__ x, const float* __restrict__ gate,
                        float* __restrict__ out) {
    int t = threadIdx.x;
    __shared__ float mx[2], sm[2], al[128], part[4][128];
    if (t < 128) {
        int w = t >> 6, l = t & 63;
        float g = gate[t];
        float m = wave_max(g);
        if (l == 0) mx[w] = m;
    }
    __syncthreads();
    if (t < 128) {
        int w = t >> 6;
        float g = gate[t];
        float m = fmaxf(mx[0], mx[1]);
        float p = expf(g - m);
        float Z = wave_sum(p);
        if (w == (t >> 6) && (t & 63) == 0) sm[w] = Z;
        al[t] = p;
    }
    __syncthreads();
    float invZ = 1.f / (sm[0] + sm[1]);
    int q = t >> 7, c = t & 127;
    float acc = 0.f;
    for (int n = q * 32; n < q * 32 + 32; n++) acc += al[n] * x[n * 128 + c];
    part[q][c] = acc * invZ;
    __syncthreads();
    if (t < 128) out[2112 + t] = part[0][t] + part[1][t] + part[2][t] + part[3][t];
}

extern "C" void kernel_launch(void* const* d_in, const int* in_sizes, int n_in,
                              void* d_out, int out_size, void* d_ws, size_t ws_size,
                              hipStream_t stream) {
    const float* feat  = (const float*)d_in[0];
    const int*   eidx  = (const int*)d_in[1];
    const float* eattr = (const float*)d_in[2];
    const float* adj   = (const float*)d_in[3];
    const float* n2n   = (const float*)d_in[4];
    const float* Wsn   = (const float*)d_in[5];
    const float* asn   = (const float*)d_in[6];
    const float* Wg    = (const float*)d_in[7];
    const float* Weg   = (const float*)d_in[8];
    const float* asrc  = (const float*)d_in[9];
    const float* adst  = (const float*)d_in[10];
    const float* aedge = (const float*)d_in[11];
    const float* Wp1   = (const float*)d_in[12];
    const float* bp1   = (const float*)d_in[13];
    const float* Wo    = (const float*)d_in[14];
    const float* Weo   = (const float*)d_in[15];
    const float* aos   = (const float*)d_in[16];
    const float* aod   = (const float*)d_in[17];
    const float* aoe   = (const float*)d_in[18];
    const float* Wp2   = (const float*)d_in[19];
    const float* bp2   = (const float*)d_in[20];
    const float* g1W   = (const float*)d_in[21];
    const float* g1b   = (const float*)d_in[22];
    const float* g2W   = (const float*)d_in[23];
    const float* g2b   = (const float*)d_in[24];
    const float* g3W   = (const float*)d_in[25];
    const float* g3b   = (const float*)d_in[26];
    float* out = (float*)d_out;

    char* ws = (char*)d_ws;
    float* h      = (float*)(ws + 0x0000000);   // 128KB
    float* z      = (float*)(ws + 0x0020000);   // 512*16*64*4 = 2MB
    float* ve1    = (float*)(ws + 0x0430000);   // 4KB
    float* ve2    = (float*)(ws + 0x0431000);   // 8KB
    float* gate1  = (float*)(ws + 0x0433000);   // 2KB
    float* gate2  = (float*)(ws + 0x0434000);   // 1KB
    float* gate3  = (float*)(ws + 0x0435000);   // 0.5KB
    float* vs1    = (float*)(ws + 0x0436000);   // 4KB
    float* vd1    = (float*)(ws + 0x0438000);   // 4KB
    float* hout1  = (float*)(ws + 0x1440000);   // 4MB
    float* d2     = (float*)(ws + 0x1840000);   // 16KB
    float* x1p    = (float*)(ws + 0x1850000);   // 2MB
    int*   winner = (int*)  (ws + 0x1A50000);   // 256KB
    float* Wh2    = (float*)(ws + 0x1A90000);   // 128KB
    float* es2    = (float*)(ws + 0x1AB0000);   // 1KB
    float* ed2    = (float*)(ws + 0x1AB1000);   // 1KB
    float* hout2  = (float*)(ws + 0x1AB2000);   // 128KB
    float* x2p    = (float*)(ws + 0x1AD2000);   // 64KB
    float* part2  = (float*)(ws + 0x1AE2000);   // 64KB
    float* part1  = (float*)(ws + 0x1AF2000);   // 2KB

    hipMemsetAsync(winner, 0xFF, 65536 * sizeof(int), stream);   // winner = -1

    k_sn     <<<512, 64, 0, stream>>>(feat, Wsn, asn, h);
    k_vecs   <<<16, 64, 0, stream>>>(Wg, Weg, asrc, adst, aedge, vs1, vd1, ve1);
    k_ve2    <<<16, 128, 0, stream>>>(Weo, aoe, ve2);
    k_scatter<<<16, 256, 0, stream>>>(eidx, winner);
    k_gate1  <<<128, 256, 0, stream>>>(h, g1W, g1b, gate1);
    k_wsum1p <<<8, 512, 0, stream>>>(h, gate1, part1);
    k_attn_z <<<512, 512, 0, stream>>>(adj, n2n, h, ve1, vs1, vd1, z);
    k_houtg  <<<dim3(64, 16), 128, 0, stream>>>(z, Wg, hout1);
    k_edot   <<<512, 256, 0, stream>>>(eattr, Weg, ve2, d2);
    k_pool1  <<<256, 256, 0, stream>>>(hout1, Wp1, bp1, x1p);
    k_gate2  <<<256, 256, 0, stream>>>(x1p, g2W, g2b, gate2);
    k_wsum2p <<<dim3(8, 8), 256, 0, stream>>>(x1p, gate2, part2);
    k_wsumr  <<<9, 256, 0, stream>>>(part1, part2, out);
    k_wh2    <<<256, 1024, 0, stream>>>(x1p, Wo, aos, aod, Wh2, es2, ed2);
    k_attn2  <<<256, 256, 0, stream>>>(winner, d2, es2, ed2, Wh2, hout2);
    k_pool2  <<<128, 128, 0, stream>>>(hout2, Wp2, bp2, x2p);
    k_gate3  <<<32, 256, 0, stream>>>(x2p, g3W, g3b, gate3);
    k_wsum3  <<<1, 512, 0, stream>>>(x2p, gate3, out);
}

// Round 7
// 144.255 us; speedup vs baseline: 1.3019x; 1.0406x over previous
//
#include <hip/hip_runtime.h>
#include <hip/hip_bf16.h>

__device__ __forceinline__ float sigm(float x) { return 1.f / (1.f + expf(-x)); }
__device__ __forceinline__ float lrelu(float x) { return x > 0.f ? x : 0.2f * x; }
__device__ __forceinline__ float eluf(float x) { return x > 0.f ? x : expf(x) - 1.f; }

#define NEGF (-9e15f)
#define MAXD 64   // max supported out-degree; P(deg>64) ~ 1e-40 for Binom(4096,1/512)

__device__ __forceinline__ float wave_sum(float v) {
    #pragma unroll
    for (int off = 32; off >= 1; off >>= 1) v += __shfl_xor(v, off);
    return v;
}
__device__ __forceinline__ float wave_max(float v) {
    #pragma unroll
    for (int off = 32; off >= 1; off >>= 1) v = fmaxf(v, __shfl_xor(v, off));
    return v;
}

// ---------------- K_setup: block-role fused independent preprocessing ----------------
// grid 176, block 256:
//   b 0..15   : vecs  (vs1/vd1/ve1 for head b), wave-cooperative coalesced
//   b 16..31  : ve2   (128 c-outputs per block), wave-cooperative coalesced
//   b 32..47  : scatter winner
//   b 48..175 : SingleNodeAttention h + gate1 (4 nodes/block, 1 wave each)
__global__ void k_setup(const float* __restrict__ Wg, const float* __restrict__ Weg,
                        const float* __restrict__ asrc, const float* __restrict__ adst,
                        const float* __restrict__ aedge, const float* __restrict__ Weo,
                        const float* __restrict__ aoe, const int* __restrict__ ei,
                        const float* __restrict__ feat, const float* __restrict__ Wsn,
                        const float* __restrict__ asn, const float* __restrict__ g1W,
                        const float* __restrict__ g1b,
                        float* __restrict__ vs1, float* __restrict__ vd1, float* __restrict__ ve1,
                        float* __restrict__ ve2, int* __restrict__ winner,
                        float* __restrict__ h, float* __restrict__ gate1) {
    int b = blockIdx.x, t = threadIdx.x, w = t >> 6, l = t & 63;
    __shared__ float fr[4][64];
    if (b < 16) {
        int hd = b;
        float s0 = asrc[hd * 128 + l],  s1 = asrc[hd * 128 + 64 + l];
        float d0 = adst[hd * 128 + l],  d1 = adst[hd * 128 + 64 + l];
        float e0 = aedge[hd * 128 + l], e1 = aedge[hd * 128 + 64 + l];
        for (int i = w; i < 64; i += 4) {
            const float* Wr = Wg  + ((size_t)hd * 64 + i) * 128;
            const float* Er = Weg + ((size_t)hd * 64 + i) * 128;
            float w1 = Wr[l], w2 = Wr[64 + l];
            float q1 = Er[l], q2 = Er[64 + l];
            float pS = wave_sum(w1 * s0 + w2 * s1);
            float pD = wave_sum(w1 * d0 + w2 * d1);
            float pE = wave_sum(q1 * e0 + q2 * e1);
            if (l == 0) { vs1[hd * 64 + i] = pS; vd1[hd * 64 + i] = pD; ve1[hd * 64 + i] = pE; }
        }
    } else if (b < 32) {
        int base = (b - 16) * 128;
        float a0 = aoe[l], a1 = aoe[64 + l];
        for (int k = 0; k < 32; k++) {
            int c = base + w * 32 + k;
            const float* Wr = Weo + (size_t)c * 128;
            float p = wave_sum(Wr[l] * a0 + Wr[64 + l] * a1);
            if (l == 0) ve2[c] = p;
        }
    } else if (b < 48) {
        int e = (b - 32) * 256 + t;
        int s = ei[e] >> 1, d = ei[4096 + e] >> 1;
        atomicMax(&winner[s * 256 + d], e);   // last edge index wins (np .set semantics)
    } else {
        int n = (b - 48) * 4 + w;
        fr[w][l] = feat[n * 64 + l];
        __syncthreads();
        float acc = 0.f;
        #pragma unroll 8
        for (int i = 0; i < 64; i++) acc += fr[w][i] * Wsn[i * 64 + l];
        float p = wave_sum(acc * asn[l]);
        float coef = sigm(lrelu(p));
        float hv = eluf(coef * acc);
        h[n * 64 + l] = hv;
        float g = wave_sum(hv * g1W[l]);
        if (l == 0) gate1[n] = sigm(g + g1b[0]);
    }
}

// ---------------- wsum1 partial: grid 8 (n-chunks), block 512 ----------------
__global__ void k_wsum1p(const float* __restrict__ h, const float* __restrict__ gate,
                         float* __restrict__ part1) {
    int nb = blockIdx.x, t = threadIdx.x, w = t >> 6, l = t & 63;
    __shared__ float mx[8], sm[8], al[512], pt[8][64];
    float g = gate[t];
    float m = wave_max(g);
    if (l == 0) mx[w] = m;
    __syncthreads();
    m = mx[0];
    #pragma unroll
    for (int i = 1; i < 8; i++) m = fmaxf(m, mx[i]);
    float p = expf(g - m);
    float Z = wave_sum(p);
    if (l == 0) sm[w] = Z;
    __syncthreads();
    Z = 0.f;
    #pragma unroll
    for (int i = 0; i < 8; i++) Z += sm[i];
    al[t] = p / Z;
    __syncthreads();
    int r0 = nb * 64 + w * 8;
    float acc = 0.f;
    #pragma unroll
    for (int r = 0; r < 8; r++) acc += al[r0 + r] * h[(r0 + r) * 64 + l];
    pt[w][l] = acc;
    __syncthreads();
    if (t < 64) {
        float o = 0.f;
        #pragma unroll
        for (int q = 0; q < 8; q++) o += pt[q][t];
        part1[nb * 64 + t] = o;
    }
}

// ---------------- K_attn_z: sparse GAT1 attention -> z[s][hd][0:64] = sum_j a*h[d_j] ----------------
// grid 512 (s), block 512
__global__ void k_attn_z(const float* __restrict__ adj, const float* __restrict__ n2n,
                         const float* __restrict__ h, const float* __restrict__ ve1,
                         const float* __restrict__ vs1, const float* __restrict__ vd1,
                         float* __restrict__ z) {
    int s = blockIdx.x, t = threadIdx.x, w = t >> 6, l = t & 63;
    __shared__ float vlT[64][17], vsT[64][17], vdT[64][17];
    __shared__ float hsr[64];
    __shared__ float hrow[MAXD][65], nrow[MAXD][65];
    __shared__ float eh[16][65], ah[16][65];
    __shared__ float es_s[16];
    __shared__ int dlist[MAXD];
    __shared__ int wbase[8];
    __shared__ int nnz_s;

    for (int idx = t; idx < 1024; idx += 512) {
        int i = idx & 63, hd = idx >> 6;
        vlT[i][hd] = ve1[hd * 64 + i];
        vsT[i][hd] = vs1[hd * 64 + i];
        vdT[i][hd] = vd1[hd * 64 + i];
    }
    if (t < 64) hsr[t] = h[s * 64 + t];
    float a = adj[s * 512 + t];
    unsigned long long mask = __ballot(a > 0.f);
    if (l == 0) wbase[w] = __popcll(mask);
    __syncthreads();
    if (t == 0) {
        int run = 0;
        #pragma unroll
        for (int i = 0; i < 8; i++) { int c = wbase[i]; wbase[i] = run; run += c; }
        nnz_s = run;
    }
    __syncthreads();
    if (a > 0.f) {
        int slot = wbase[w] + __popcll(mask & ((1ULL << l) - 1ULL));
        if (slot < MAXD) dlist[slot] = t;
    }
    __syncthreads();
    int nnz = min(nnz_s, MAXD);

    if (nnz == 0) {
        __shared__ float part[8][64];
        int i = t & 63, q = t >> 6;
        float acc = 0.f;
        for (int d = q * 64; d < q * 64 + 64; d++) acc += h[d * 64 + i];
        part[q][i] = acc;
        __syncthreads();
        if (t < 64) {
            float sum = 0.f;
            #pragma unroll
            for (int q2 = 0; q2 < 8; q2++) sum += part[q2][t];
            float v = sum * (1.f / 512.f);
            for (int hd = 0; hd < 16; hd++) z[(size_t)s * 1024 + hd * 64 + t] = v;
        }
        return;
    }

    for (int base = 0; base < nnz; base += 8) {
        int j = base + (t >> 6);
        if (j < nnz) {
            int d = dlist[j];
            hrow[j][l] = h[d * 64 + l];
            nrow[j][l] = n2n[((size_t)s * 512 + d) * 64 + l];
        }
    }
    if (t < 16) {
        float acc = 0.f;
        for (int i = 0; i < 64; i++) acc += hsr[i] * vsT[i][t];
        es_s[t] = acc;
    }
    __syncthreads();
    for (int jb = 0; jb < nnz; jb += 32) {
        int j = jb + (t >> 4), hd = t & 15;
        if (j < nnz) {
            float ee = 0.f, edv = 0.f;
            #pragma unroll 8
            for (int i = 0; i < 64; i++) {
                ee  += nrow[j][i] * vlT[i][hd];
                edv += hrow[j][i] * vdT[i][hd];
            }
            eh[hd][j] = lrelu(es_s[hd] + edv + ee);
        }
    }
    __syncthreads();
    if (t < 16) {
        float m = -1e30f;
        for (int j = 0; j < nnz; j++) m = fmaxf(m, eh[t][j]);
        float Z = 0.f;
        for (int j = 0; j < nnz; j++) { float p = expf(eh[t][j] - m); ah[t][j] = p; Z += p; }
        float inv = 1.f / Z;
        for (int j = 0; j < nnz; j++) ah[t][j] *= inv;
    }
    __syncthreads();
    int hd = t >> 5, i0 = t & 31;
    float a0 = 0.f, a1 = 0.f;
    for (int j = 0; j < nnz; j++) {
        float aj = ah[hd][j];
        a0 += aj * hrow[j][i0];
        a1 += aj * hrow[j][i0 + 32];
    }
    z[(size_t)s * 1024 + hd * 64 + i0]      = a0;
    z[(size_t)s * 1024 + hd * 64 + i0 + 32] = a1;
}

// ---------------- K_houtg: hout[s][hd*128+c] = elu( z[s][hd]·Wg[hd][:,c] ) ----------------
// grid (64 s-tiles, 16 hd), block 128
__global__ void k_houtg(const float* __restrict__ z, const float* __restrict__ Wg,
                        float* __restrict__ hout) {
    int sb = blockIdx.x, hd = blockIdx.y, c = threadIdx.x;
    __shared__ float zt[8][64];
    int s0 = sb * 8;
    for (int idx = c; idx < 512; idx += 128) {
        int r = idx >> 6, i = idx & 63;
        zt[r][i] = z[(size_t)(s0 + r) * 1024 + hd * 64 + i];
    }
    __syncthreads();
    float acc[8] = {0, 0, 0, 0, 0, 0, 0, 0};
    const float* W = Wg + (size_t)hd * 8192 + c;
    #pragma unroll 8
    for (int i = 0; i < 64; i++) {
        float wv = W[(size_t)i * 128];
        #pragma unroll
        for (int r = 0; r < 8; r++) acc[r] += zt[r][i] * wv;
    }
    #pragma unroll
    for (int r = 0; r < 8; r++)
        hout[(size_t)(s0 + r) * 2048 + hd * 128 + c] = eluf(acc[r]);
}

// ---------------- K8: per-edge d2[e] = sum_c elu(edge_attr[e] @ Weg)[c] * ve2[c] ----------------
// grid 512 (8 edges/block), block 256
__global__ void k_edot(const float* __restrict__ eattr, const float* __restrict__ Weg,
                       const float* __restrict__ ve2, float* __restrict__ d2) {
    int e0 = blockIdx.x * 8, t = threadIdx.x;
    int w = t >> 6, l = t & 63;
    __shared__ float ea[8][64];
    __shared__ float sd[8][4];
    for (int idx = t; idx < 8 * 64; idx += 256)
        ea[idx >> 6][idx & 63] = eattr[(size_t)(e0 + (idx >> 6)) * 64 + (idx & 63)];
    __syncthreads();
    int hd = t >> 4, o0 = (t & 15) * 8;
    float acc[8][8];
    #pragma unroll
    for (int r = 0; r < 8; r++)
        #pragma unroll
        for (int j = 0; j < 8; j++) acc[r][j] = 0.f;
    const float* W = Weg + (size_t)hd * 64 * 128 + o0;
    for (int i = 0; i < 64; i++) {
        float wv[8];
        #pragma unroll
        for (int j = 0; j < 8; j++) wv[j] = W[i * 128 + j];
        #pragma unroll
        for (int r = 0; r < 8; r++) {
            float a = ea[r][i];
            #pragma unroll
            for (int j = 0; j < 8; j++) acc[r][j] += a * wv[j];
        }
    }
    float v2[8];
    #pragma unroll
    for (int j = 0; j < 8; j++) v2[j] = ve2[hd * 128 + o0 + j];
    #pragma unroll
    for (int r = 0; r < 8; r++) {
        float p = 0.f;
        #pragma unroll
        for (int j = 0; j < 8; j++) p += eluf(acc[r][j]) * v2[j];
        p = wave_sum(p);
        if (l == 0) sd[r][w] = p;
    }
    __syncthreads();
    if (t < 8) d2[e0 + t] = sd[t][0] + sd[t][1] + sd[t][2] + sd[t][3];
}

// ---------------- K9: edge_pool1 + gate2 fused ----------------
// grid 256, block 256
__global__ void k_pool1g2(const float* __restrict__ x, const float* __restrict__ Wp,
                          const float* __restrict__ bp, const float* __restrict__ g2W,
                          const float* __restrict__ g2b,
                          float* __restrict__ xo, float* __restrict__ gate2) {
    int k = blockIdx.x, t = threadIdx.x, w = t >> 6, l = t & 63;
    __shared__ float sd[4], sg[4];
    float p = 0.f;
    for (int f = t; f < 2048; f += 256)
        p += x[(size_t)(2 * k) * 2048 + f] * Wp[f] + x[(size_t)(2 * k + 1) * 2048 + f] * Wp[2048 + f];
    p = wave_sum(p);
    if (l == 0) sd[w] = p;
    __syncthreads();
    float sc = sigm(sd[0] + sd[1] + sd[2] + sd[3] + bp[0]);
    float pg = 0.f;
    for (int f = t; f < 2048; f += 256) {
        float v = x[(size_t)(2 * k) * 2048 + f] + x[(size_t)(2 * k + 1) * 2048 + f];
        xo[(size_t)k * 2048 + f] = v * sc;
        pg += v * g2W[f];
    }
    pg = wave_sum(pg);
    if (l == 0) sg[w] = pg;
    __syncthreads();
    if (t == 0) gate2[k] = sigm(sc * (sg[0] + sg[1] + sg[2] + sg[3]) + g2b[0]);
}

// ---------------- wsum2 partial: grid (8 col-blk, 8 n-blk), block 256 ----------------
__global__ void k_wsum2p(const float* __restrict__ x, const float* __restrict__ gate,
                         float* __restrict__ part2) {
    int t = threadIdx.x, w = t >> 6, l = t & 63;
    __shared__ float mx[4], sm[4], al[256];
    float g = gate[t];
    float m = wave_max(g);
    if (l == 0) mx[w] = m;
    __syncthreads();
    m = fmaxf(fmaxf(mx[0], mx[1]), fmaxf(mx[2], mx[3]));
    float p = expf(g - m);
    float Z = wave_sum(p);
    if (l == 0) sm[w] = Z;
    __syncthreads();
    Z = sm[0] + sm[1] + sm[2] + sm[3];
    al[t] = p / Z;
    __syncthreads();
    int c = blockIdx.x * 256 + t;
    int n0 = blockIdx.y * 32;
    float acc = 0.f;
    #pragma unroll 8
    for (int n = n0; n < n0 + 32; n++) acc += al[n] * x[(size_t)n * 2048 + c];
    part2[blockIdx.y * 2048 + c] = acc;
}

// ---------------- reducer for wsum1 + wsum2 ----------------
// grid 9, block 256
__global__ void k_wsumr(const float* __restrict__ part1, const float* __restrict__ part2,
                        float* __restrict__ out) {
    int b = blockIdx.x, t = threadIdx.x;
    if (b == 0) {
        if (t < 64) {
            float o = 0.f;
            #pragma unroll
            for (int nb = 0; nb < 8; nb++) o += part1[nb * 64 + t];
            out[t] = o;
        }
    } else {
        int c = (b - 1) * 256 + t;
        float o = 0.f;
        #pragma unroll
        for (int nb = 0; nb < 8; nb++) o += part2[nb * 2048 + c];
        out[64 + c] = o;
    }
}

// ---------------- K11: Wh2 = x1p @ Wo, es2/ed2 — 2 rows/block, K-split ----------------
// grid 128, block 1024: ks = t>>7 (8 K-slices of 256), c = t&127
__global__ void k_wh2(const float* __restrict__ x, const float* __restrict__ Wo,
                      const float* __restrict__ aos, const float* __restrict__ aod,
                      float* __restrict__ Wh2, float* __restrict__ es2, float* __restrict__ ed2) {
    int n0 = blockIdx.x * 2, t = threadIdx.x;
    int ks = t >> 7, c = t & 127;
    __shared__ float xr[2][2048];
    __shared__ float part[8][2][128];
    __shared__ float rs[4], rd[4];
    for (int idx = t; idx < 4096; idx += 1024) xr[idx >> 11][idx & 2047] = x[(size_t)n0 * 2048 + idx];
    __syncthreads();
    float a0 = 0.f, a1 = 0.f;
    const float* W  = Wo + (size_t)(ks * 256) * 128 + c;
    const float* x0 = xr[0] + ks * 256;
    const float* x1 = xr[1] + ks * 256;
    #pragma unroll 8
    for (int i = 0; i < 256; i++) { float w = W[(size_t)i * 128]; a0 += x0[i] * w; a1 += x1[i] * w; }
    part[ks][0][c] = a0;
    part[ks][1][c] = a1;
    __syncthreads();
    if (t < 256) {
        int r = t >> 7, cc = t & 127;
        float a = 0.f;
        #pragma unroll
        for (int k = 0; k < 8; k++) a += part[k][r][cc];
        Wh2[(n0 + r) * 128 + cc] = a;
        float ps = wave_sum(a * aos[cc]);
        float pd = wave_sum(a * aod[cc]);
        if ((t & 63) == 0) { rs[t >> 6] = ps; rd[t >> 6] = pd; }
    }
    __syncthreads();
    if (t == 0) { es2[n0] = rs[0] + rs[1]; ed2[n0] = rd[0] + rd[1]; }
    if (t == 1) { es2[n0 + 1] = rs[2] + rs[3]; ed2[n0 + 1] = rd[2] + rd[3]; }
}

// ---------------- K12: GAT2 attention + hout2 ----------------
// grid 256, block 256
__global__ void k_attn2(const int* __restrict__ winner, const float* __restrict__ d2,
                        const float* __restrict__ es2, const float* __restrict__ ed2,
                        const float* __restrict__ Wh2, float* __restrict__ hout2) {
    int s = blockIdx.x, t = threadIdx.x, w = t >> 6, l = t & 63;
    __shared__ float mx[4], sm[4], at[256], part[2][128];
    int win = winner[s * 256 + t];
    float e;
    if (win >= 0) e = lrelu(es2[s] + ed2[t] + d2[win]);
    else e = NEGF;
    float m = wave_max(e);
    if (l == 0) mx[w] = m;
    __syncthreads();
    m = fmaxf(fmaxf(mx[0], mx[1]), fmaxf(mx[2], mx[3]));
    float p = expf(e - m);
    float Z = wave_sum(p);
    if (l == 0) sm[w] = Z;
    __syncthreads();
    Z = sm[0] + sm[1] + sm[2] + sm[3];
    at[t] = p / Z;
    __syncthreads();
    int c = t & 127, hf = t >> 7;
    float acc = 0.f;
    for (int d = hf * 128; d < hf * 128 + 128; d++)
        acc += at[d] * Wh2[d * 128 + c];
    part[hf][c] = acc;
    __syncthreads();
    if (t < 128) hout2[s * 128 + t] = part[0][t] + part[1][t];   // concat=False: no elu
}

// ---------------- K13: edge_pool2 + gate3 fused ----------------
// grid 128, block 128
__global__ void k_pool2g3(const float* __restrict__ x, const float* __restrict__ Wp,
                          const float* __restrict__ bp, const float* __restrict__ g3W,
                          const float* __restrict__ g3b,
                          float* __restrict__ xo, float* __restrict__ gate3) {
    int k = blockIdx.x, t = threadIdx.x;
    __shared__ float r[2], rg[2];
    float a0 = x[(size_t)(2 * k) * 128 + t];
    float a1 = x[(size_t)(2 * k + 1) * 128 + t];
    float p = wave_sum(a0 * Wp[t] + a1 * Wp[128 + t]);
    if ((t & 63) == 0) r[t >> 6] = p;
    __syncthreads();
    float sc = sigm(r[0] + r[1] + bp[0]);
    float v = (a0 + a1) * sc;
    xo[k * 128 + t] = v;
    float pg = wave_sum(v * g3W[t]);
    if ((t & 63) == 0) rg[t >> 6] = pg;
    __syncthreads();
    if (t == 0) gate3[k] = sigm(rg[0] + rg[1] + g3b[0]);
}

// ---------------- wsum3: out[2112+c], in-block n-split ----------------
// grid 1, block 512
__global__ void k_wsum3(const float* __restrict__ x, const float* __restrict__ gate,
                        float* __restrict__ out) {
    int t = threadIdx.x;
    __shared__ float mx[2], sm[2], al[128], part[4][128];
    if (t < 128) {
        int w = t >> 6, l = t & 63;
        float g = gate[t];
        float m = wave_max(g);
        if (l == 0) mx[w] = m;
    }
    __syncthreads();
    if (t < 128) {
        int w = t >> 6;
        float g = gate[t];
        float m = fmaxf(mx[0], mx[1]);
        float p = expf(g - m);
        float Z = wave_sum(p);
        if ((t & 63) == 0) sm[w] = Z;
        al[t] = p;
    }
    __syncthreads();
    float invZ = 1.f / (sm[0] + sm[1]);
    int q = t >> 7, c = t & 127;
    float acc = 0.f;
    for (int n = q * 32; n < q * 32 + 32; n++) acc += al[n] * x[n * 128 + c];
    part[q][c] = acc * invZ;
    __syncthreads();
    if (t < 128) out[2112 + t] = part[0][t] + part[1][t] + part[2][t] + part[3][t];
}

extern "C" void kernel_launch(void* const* d_in, const int* in_sizes, int n_in,
                              void* d_out, int out_size, void* d_ws, size_t ws_size,
                              hipStream_t stream) {
    const float* feat  = (const float*)d_in[0];
    const int*   eidx  = (const int*)d_in[1];
    const float* eattr = (const float*)d_in[2];
    const float* adj   = (const float*)d_in[3];
    const float* n2n   = (const float*)d_in[4];
    const float* Wsn   = (const float*)d_in[5];
    const float* asn   = (const float*)d_in[6];
    const float* Wg    = (const float*)d_in[7];
    const float* Weg   = (const float*)d_in[8];
    const float* asrc  = (const float*)d_in[9];
    const float* adst  = (const float*)d_in[10];
    const float* aedge = (const float*)d_in[11];
    const float* Wp1   = (const float*)d_in[12];
    const float* bp1   = (const float*)d_in[13];
    const float* Wo    = (const float*)d_in[14];
    const float* Weo   = (const float*)d_in[15];
    const float* aos   = (const float*)d_in[16];
    const float* aod   = (const float*)d_in[17];
    const float* aoe   = (const float*)d_in[18];
    const float* Wp2   = (const float*)d_in[19];
    const float* bp2   = (const float*)d_in[20];
    const float* g1W   = (const float*)d_in[21];
    const float* g1b   = (const float*)d_in[22];
    const float* g2W   = (const float*)d_in[23];
    const float* g2b   = (const float*)d_in[24];
    const float* g3W   = (const float*)d_in[25];
    const float* g3b   = (const float*)d_in[26];
    float* out = (float*)d_out;

    char* ws = (char*)d_ws;
    float* h      = (float*)(ws + 0x0000000);   // 128KB
    float* z      = (float*)(ws + 0x0020000);   // 2MB
    float* ve1    = (float*)(ws + 0x0430000);   // 4KB
    float* ve2    = (float*)(ws + 0x0431000);   // 8KB
    float* gate1  = (float*)(ws + 0x0433000);   // 2KB
    float* gate2  = (float*)(ws + 0x0434000);   // 1KB
    float* gate3  = (float*)(ws + 0x0435000);   // 0.5KB
    float* vs1    = (float*)(ws + 0x0436000);   // 4KB
    float* vd1    = (float*)(ws + 0x0438000);   // 4KB
    float* hout1  = (float*)(ws + 0x1440000);   // 4MB
    float* d2     = (float*)(ws + 0x1840000);   // 16KB
    float* x1p    = (float*)(ws + 0x1850000);   // 2MB
    int*   winner = (int*)  (ws + 0x1A50000);   // 256KB
    float* Wh2    = (float*)(ws + 0x1A90000);   // 128KB
    float* es2    = (float*)(ws + 0x1AB0000);   // 1KB
    float* ed2    = (float*)(ws + 0x1AB1000);   // 1KB
    float* hout2  = (float*)(ws + 0x1AB2000);   // 128KB
    float* x2p    = (float*)(ws + 0x1AD2000);   // 64KB
    float* part2  = (float*)(ws + 0x1AE2000);   // 64KB
    float* part1  = (float*)(ws + 0x1AF2000);   // 2KB

    hipMemsetAsync(winner, 0xFF, 65536 * sizeof(int), stream);   // winner = -1

    k_setup   <<<176, 256, 0, stream>>>(Wg, Weg, asrc, adst, aedge, Weo, aoe, eidx,
                                        feat, Wsn, asn, g1W, g1b,
                                        vs1, vd1, ve1, ve2, winner, h, gate1);
    k_wsum1p  <<<8, 512, 0, stream>>>(h, gate1, part1);
    k_attn_z  <<<512, 512, 0, stream>>>(adj, n2n, h, ve1, vs1, vd1, z);
    k_houtg   <<<dim3(64, 16), 128, 0, stream>>>(z, Wg, hout1);
    k_edot    <<<512, 256, 0, stream>>>(eattr, Weg, ve2, d2);
    k_pool1g2 <<<256, 256, 0, stream>>>(hout1, Wp1, bp1, g2W, g2b, x1p, gate2);
    k_wsum2p  <<<dim3(8, 8), 256, 0, stream>>>(x1p, gate2, part2);
    k_wsumr   <<<9, 256, 0, stream>>>(part1, part2, out);
    k_wh2     <<<128, 1024, 0, stream>>>(x1p, Wo, aos, aod, Wh2, es2, ed2);
    k_attn2   <<<256, 256, 0, stream>>>(winner, d2, es2, ed2, Wh2, hout2);
    k_pool2g3 <<<128, 128, 0, stream>>>(hout2, Wp2, bp2, g3W, g3b, x2p, gate3);
    k_wsum3   <<<1, 512, 0, stream>>>(x2p, gate3, out);
}